// Round 2
// baseline (269.044 us; speedup 1.0000x reference)
//
#include <hip/hip_runtime.h>
#include <math.h>

#define Nn      2000
#define Ee      2000
#define EMBED   256
#define HIDDEN  512
#define KDIM    512     // MFMA K (embedding part only; dist handled in epilogue)
#define BM      64      // edges per workgroup
#define NTHREADS 512    // 8 waves
#define NWG     4000    // 4000 * 64 = 256000 edges exactly

typedef __attribute__((ext_vector_type(8)))  short bf16x8;
typedef __attribute__((ext_vector_type(16))) float f32x16;

static __device__ __forceinline__ short f2bf(float f) {
  unsigned u = __builtin_bit_cast(unsigned, f);
  u += 0x7fffu + ((u >> 16) & 1u);
  return (short)(u >> 16);
}

static __device__ __forceinline__ bf16x8 cvt8(float4 a, float4 b) {
  bf16x8 v;
  v[0]=f2bf(a.x); v[1]=f2bf(a.y); v[2]=f2bf(a.z); v[3]=f2bf(a.w);
  v[4]=f2bf(b.x); v[5]=f2bf(b.y); v[6]=f2bf(b.z); v[7]=f2bf(b.w);
  return v;
}

// ---------------- prep: W1 (513x512 f32 [k][n]) -> W1T bf16 [n][k], k<512 ----
__global__ void w1t_kernel(const float* __restrict__ W1, short* __restrict__ W1T) {
  __shared__ float t[32][33];
  const int kt = blockIdx.x & 15;   // k-tile
  const int nt = blockIdx.x >> 4;   // n-tile
  const int tx = threadIdx.x & 31;
  const int ty = threadIdx.x >> 5;  // 0..7
#pragma unroll
  for (int r = 0; r < 32; r += 8)
    t[ty + r][tx] = W1[(kt * 32 + ty + r) * HIDDEN + nt * 32 + tx];
  __syncthreads();
#pragma unroll
  for (int r = 0; r < 32; r += 8)
    W1T[(nt * 32 + ty + r) * KDIM + kt * 32 + tx] = f2bf(t[tx][ty + r]);
}

// ---------------- main fused kernel ----------------
__global__ __launch_bounds__(NTHREADS, 4)   // cap ~128 regs -> 2 blocks/CU
void edge_kernel(const float* __restrict__ emb, const float* __restrict__ locs,
                 const int* __restrict__ edges, const int* __restrict__ dbias,
                 const float* __restrict__ W1, const float* __restrict__ b1,
                 const float* __restrict__ W2, const float* __restrict__ b2,
                 const short* __restrict__ W1T, float* __restrict__ out)
{
  // LDS ~= 29.7 KB -> occupancy reg-limited, not LDS-limited
  __shared__ short  A_lds[2][BM][72];   // feats chunk tile, bf16, pad 64->72
  __shared__ float4 ep_s[HIDDEN];       // {b1[n], W1[512][n], W2[n], 0}
  __shared__ float  dist_s[BM];
  __shared__ int    valid_s[BM];
  __shared__ int    ibase_s[BM];
  __shared__ int    jbase_s[BM];
  __shared__ float  part_s[8][BM];

  const int tid = threadIdx.x;
  const int bid = blockIdx.x;
  // chunked XCD swizzle (bijective: 4000 = 8 * 500): keep one batch's
  // embedding rows resident in one XCD's L2
  const int wg  = (bid & 7) * (NWG / 8) + (bid >> 3);

  if (tid < BM) {
    const int g  = wg * BM + tid;         // flat edge id = b*Ee + e
    const int b  = g / Ee;
    const int i0 = edges[2 * (size_t)g];
    const int j0 = edges[2 * (size_t)g + 1];
    valid_s[tid] = (i0 >= 0) && (j0 >= 0);
    const int ib = b * Nn + (i0 < 0 ? 0 : i0);
    const int jb = b * Nn + (j0 < 0 ? 0 : j0);
    ibase_s[tid] = ib;
    jbase_s[tid] = jb;
    const float dx = locs[2 * (size_t)ib]     - locs[2 * (size_t)jb];
    const float dy = locs[2 * (size_t)ib + 1] - locs[2 * (size_t)jb + 1];
    dist_s[tid] = sqrtf(dx * dx + dy * dy);
  }
  ep_s[tid] = make_float4(b1[tid], W1[(size_t)KDIM * HIDDEN + tid], W2[tid], 0.f);
  __syncthreads();

  const int lane = tid & 63;
  const int wv   = tid >> 6;        // wave id 0..7 -> hidden slice [wv*64, +64)
  const int ln31 = lane & 31;
  const int kg   = lane >> 5;       // k-half for MFMA fragments

  const short* pA0 = W1T + ((size_t)(wv * 64 + ln31) * KDIM) + kg * 8;
  const short* pA1 = pA0 + 32 * (size_t)KDIM;

  // staging: 8 threads per edge, 32 B (8 floats) each per chunk
  const int se = tid >> 3;          // edge 0..63
  const int sq = tid & 7;

  const float* pi = emb + (size_t)ibase_s[se] * EMBED + sq * 8;
  const float* pj = emb + (size_t)jbase_s[se] * EMBED + sq * 8;

  f32x16 acc[2][2];                 // [edge-tile][n-tile]
#pragma unroll
  for (int et = 0; et < 2; ++et)
#pragma unroll
    for (int nt = 0; nt < 2; ++nt)
#pragma unroll
      for (int q = 0; q < 16; ++q) acc[et][nt][q] = 0.f;

  // ---- prologue: gather chunk 0, write buf0; leave chunk 1 in flight ----
  float4 sB0, sB1;
  sB0 = *(const float4*)(pi);
  sB1 = *(const float4*)(pi + 4);
  *(bf16x8*)&A_lds[0][se][sq * 8] = cvt8(sB0, sB1);
  sB0 = *(const float4*)(pi + 64);
  sB1 = *(const float4*)(pi + 64 + 4);
  __syncthreads();

  // ---- K loop: 8 chunks of 64 ----
#pragma unroll
  for (int c = 0; c < 8; ++c) {
    // 1) land held gather (chunk c+1) into the other buffer
    if (c < 7)
      *(bf16x8*)&A_lds[(c + 1) & 1][se][sq * 8] = cvt8(sB0, sB1);

    // 2) W1T loads for this chunk BEFORE issuing new gathers, so the
    //    vmcnt wait for them doesn't drain the slow gathers
    bf16x8 wa0[4], wa1[4];
#pragma unroll
    for (int ks = 0; ks < 4; ++ks) {
      wa0[ks] = *(const bf16x8*)(pA0 + c * 64 + ks * 16);
      wa1[ks] = *(const bf16x8*)(pA1 + c * 64 + ks * 16);
    }

    // 3) issue gather for chunk c+2 (held in regs until next iteration)
    if (c < 6) {
      const int cc = c + 2;
      const float* p = (cc < 4 ? pi : pj) + (cc & 3) * 64;
      sB0 = *(const float4*)(p);
      sB1 = *(const float4*)(p + 4);
    }

    // 4) MFMA over current buffer
    const short* Ab = &A_lds[c & 1][0][0];
#pragma unroll
    for (int ks = 0; ks < 4; ++ks) {
#pragma unroll
      for (int et = 0; et < 2; ++et) {
        bf16x8 fb = *(const bf16x8*)(Ab + (et * 32 + ln31) * 72 + ks * 16 + kg * 8);
        acc[et][0] = __builtin_amdgcn_mfma_f32_32x32x16_bf16(wa0[ks], fb, acc[et][0], 0, 0, 0);
        acc[et][1] = __builtin_amdgcn_mfma_f32_32x32x16_bf16(wa1[ks], fb, acc[et][1], 0, 0, 0);
      }
    }
    __syncthreads();
  }

  // ---- epilogue: dist column + bias + relu + dot W2 (in-lane over n) ----
  const float d0 = dist_s[ln31];
  const float d1 = dist_s[32 + ln31];
  float ps0 = 0.f, ps1 = 0.f;
#pragma unroll
  for (int nt = 0; nt < 2; ++nt) {
#pragma unroll
    for (int r = 0; r < 16; ++r) {
      const int n = wv * 64 + nt * 32 + (r & 3) + ((r >> 2) << 3) + (kg << 2);
      const float4 ep = ep_s[n];
      float p0 = acc[0][nt][r] + ep.x + d0 * ep.y;
      float p1 = acc[1][nt][r] + ep.x + d1 * ep.y;
      ps0 += fmaxf(p0, 0.f) * ep.z;
      ps1 += fmaxf(p1, 0.f) * ep.z;
    }
  }
  ps0 += __shfl_xor(ps0, 32, 64);
  ps1 += __shfl_xor(ps1, 32, 64);
  if (lane < 32) {
    part_s[wv][ln31]      = ps0;
    part_s[wv][32 + ln31] = ps1;
  }
  __syncthreads();

  if (tid < BM) {
    float s = part_s[0][tid];
#pragma unroll
    for (int w = 1; w < 8; ++w) s += part_s[w][tid];
    float logit = s + b2[0] + (float)dbias[0];
    if (!valid_s[tid]) logit = -__builtin_inff();
    out[(size_t)wg * BM + tid] = logit;
  }
}

extern "C" void kernel_launch(void* const* d_in, const int* in_sizes, int n_in,
                              void* d_out, int out_size, void* d_ws, size_t ws_size,
                              hipStream_t stream) {
  const float* emb   = (const float*)d_in[0];
  const float* locs  = (const float*)d_in[1];
  const int*   edges = (const int*)d_in[2];
  const int*   dbias = (const int*)d_in[3];
  const float* W1    = (const float*)d_in[4];
  const float* b1    = (const float*)d_in[5];
  const float* W2    = (const float*)d_in[6];
  const float* b2    = (const float*)d_in[7];
  float*       out   = (float*)d_out;
  short*       W1T   = (short*)d_ws;   // 512*512*2 = 512 KiB

  w1t_kernel<<<dim3(256), dim3(256), 0, stream>>>(W1, W1T);
  edge_kernel<<<dim3(NWG), dim3(NTHREADS), 0, stream>>>(
      emb, locs, edges, dbias, W1, b1, W2, b2, (const short*)W1T, out);
}